// Round 8
// baseline (139.918 us; speedup 1.0000x reference)
//
#include <hip/hip_runtime.h>
#include <hip/hip_bf16.h>

typedef __bf16 bf16_t;
typedef __bf16 bf16x8 __attribute__((ext_vector_type(8)));
typedef float  f32x4  __attribute__((ext_vector_type(4)));

#define MFMA16(a, b, c) __builtin_amdgcn_mfma_f32_16x16x32_bf16((a), (b), (c), 0, 0, 0)

constexpr int Bc = 4, Lc = 2048, Hc = 8, Dc = 64;
constexpr int HD = Hc * Dc;            // 512
constexpr int TRAINc = 1536;
constexpr float QSCALE = 0.125f * 1.4426950408889634f;   // 1/sqrt(64) * log2(e)

// ---------------- merged prep: K fp32->bf16 copy; V fp32 -> bf16 [b][h][d][key] ----------------
__global__ void prep_kv(const float* __restrict__ K, const float* __restrict__ V,
                        bf16_t* __restrict__ Kb, bf16_t* __restrict__ Vt) {
  __shared__ bf16_t T[64][72];
  const int bid0 = blockIdx.x;
  const int t = (int)threadIdx.x;
  if (bid0 < 2048) {                    // K convert, layout unchanged
    size_t g = ((size_t)bid0 * 256 + t) * 8;
    float4 a = *(const float4*)(K + g);
    float4 b = *(const float4*)(K + g + 4);
    bf16x8 v;
    v[0] = (bf16_t)a.x; v[1] = (bf16_t)a.y; v[2] = (bf16_t)a.z; v[3] = (bf16_t)a.w;
    v[4] = (bf16_t)b.x; v[5] = (bf16_t)b.y; v[6] = (bf16_t)b.z; v[7] = (bf16_t)b.w;
    *(bf16x8*)(Kb + g) = v;
    return;
  }
  const int bid = bid0 - 2048;          // V transpose
  const int kt = bid & 31, h = (bid >> 5) & 7, b = bid >> 8;
  {
    int kl = t >> 2, dp = (t & 3) << 4;
    const float* s = V + ((size_t)(b * Lc + kt * 64 + kl) * Hc + h) * Dc + dp;
    bf16x8 v0, v1;
    float4 f;
    f = *(const float4*)(s);      v0[0]=(bf16_t)f.x; v0[1]=(bf16_t)f.y; v0[2]=(bf16_t)f.z; v0[3]=(bf16_t)f.w;
    f = *(const float4*)(s + 4);  v0[4]=(bf16_t)f.x; v0[5]=(bf16_t)f.y; v0[6]=(bf16_t)f.z; v0[7]=(bf16_t)f.w;
    f = *(const float4*)(s + 8);  v1[0]=(bf16_t)f.x; v1[1]=(bf16_t)f.y; v1[2]=(bf16_t)f.z; v1[3]=(bf16_t)f.w;
    f = *(const float4*)(s + 12); v1[4]=(bf16_t)f.x; v1[5]=(bf16_t)f.y; v1[6]=(bf16_t)f.z; v1[7]=(bf16_t)f.w;
    *(bf16x8*)&T[kl][dp] = v0;
    *(bf16x8*)&T[kl][dp + 8] = v1;
  }
  __syncthreads();
  {
    int d = t >> 2, kp = (t & 3) << 4;
    bf16x8 o0, o1;
#pragma unroll
    for (int i = 0; i < 8; ++i) { o0[i] = T[kp + i][d]; o1[i] = T[kp + 8 + i][d]; }
    bf16_t* dst = Vt + ((size_t)((b * Hc + h) * Dc + d)) * Lc + kt * 64 + kp;
    *(bf16x8*)dst = o0;
    *(bf16x8*)(dst + 8) = o1;
  }
}

// ---------------- main attention ----------------
static __device__ __forceinline__ void load16(const bf16_t* g, bf16_t* l) {
  __builtin_amdgcn_global_load_lds(
      (const __attribute__((address_space(1))) unsigned int*)g,
      (__attribute__((address_space(3))) unsigned int*)l, 16, 0, 0);
}

__global__ __launch_bounds__(128, 2)
void continual_attn(const float* __restrict__ Qg, const bf16_t* __restrict__ Kb,
                    const bf16_t* __restrict__ Vt, const int* __restrict__ ATT,
                    float* __restrict__ OUT)
{
  // Rows of 64 bf16 (128B); 16B slot s of row r holds logical slot s^(r&7).
  // LDS = 16+16+8 KB = 40960 B -> exactly 4 blocks/CU; grid 1024 all resident.
  __shared__ __align__(16) bf16_t Klds[2][64 * 64];   // 16 KB
  __shared__ __align__(16) bf16_t Vlds[2][64 * 64];   // 16 KB
  __shared__ __align__(16) bf16_t Plds[2][32 * 64];   // 8 KB (per wave: 32 q rows)

  const int bid  = blockIdx.x;
  const int qblk = 31 - (bid >> 5);   // heavy q-blocks first
  const int h    = bid & 7;
  const int b    = (bid >> 3) & 3;
  const int q0   = qblk * 64;

  const int tid  = (int)threadIdx.x;  // 0..127 (2 waves)
  const int wave = tid >> 6;
  const int lane = tid & 63;
  const int quad = lane >> 4;
  const int col  = lane & 15;
  const int qw   = q0 + wave * 32;    // this wave's 32 q rows (2 row-blocks of 16)

  // ---- per-row mask parameters, per row-block rb: qi = qw + rb*16 + quad*4 + r ----
  const bool testblk = (q0 >= TRAINc);
  int kend[2][4], cstart[2][4], qir[2][4];
#pragma unroll
  for (int rb = 0; rb < 2; ++rb) {
#pragma unroll
    for (int r = 0; r < 4; ++r) {
      int qi = qw + rb * 16 + quad * 4 + r;
      qir[rb][r] = qi;
      if (testblk) {
        kend[rb][r]   = ATT[b * 64 + ((qi - TRAINc) >> 3)] + 1;
        cstart[rb][r] = qi & ~7;
      } else {
        kend[rb][r]   = qi + 1;
        cstart[rb][r] = 0;
      }
    }
  }

  int ntA, ntot, kfull_end;
  if (testblk) {
    int c0 = (q0 - TRAINc) >> 3;
    int amax = 0;
#pragma unroll
    for (int i = 0; i < 8; ++i) {
      int a = ATT[b * 64 + c0 + i];
      amax = (a > amax) ? a : amax;
    }
    int w0 = (qw - TRAINc) >> 3;      // this wave's 4 chunks
    int amin = 0x7fffffff;
#pragma unroll
    for (int i = 0; i < 4; ++i) {
      int a = ATT[b * 64 + w0 + i];
      amin = (a < amin) ? a : amin;
    }
    kfull_end = amin + 1;
    ntA = (amax >> 6) + 1;            // block-uniform tile count over [0, amax]
    ntot = ntA + 1;                   // + diagonal tile at k0=q0
  } else {
    ntA = qblk + 1;
    ntot = ntA;
    kfull_end = qw + 1;               // wave-uniform causal bound
  }

  const size_t bhQ = (size_t)b * Lc * HD + (size_t)h * Dc;

  // ---- staging source pointers (XOR swizzle folded into source address) ----
  // 128 threads stage 16 rows per load16 call; c-loop covers 64 rows.
  const int kr = tid >> 3;            // 0..15
  const int sl = ((tid & 7) ^ (kr & 7)) << 3;
  const bf16_t* ksrc0 = Kb + bhQ + (size_t)kr * HD + sl;
  const bf16_t* vsrc0 = Vt + ((size_t)((b * Hc + h) * Dc + kr)) * Lc + sl;

  // ---- Q fragments per row-block (A-layout: row=col, k=quad*8+j), scaled ----
  bf16x8 aq[2][2];
#pragma unroll
  for (int rb = 0; rb < 2; ++rb) {
    const float* qp = Qg + bhQ + (size_t)(qw + rb * 16 + col) * HD + quad * 8;
#pragma unroll
    for (int t = 0; t < 2; ++t) {
      float4 lo = *(const float4*)(qp + t * 32);
      float4 hi = *(const float4*)(qp + t * 32 + 4);
      bf16x8 v;
      v[0] = (bf16_t)(lo.x * QSCALE); v[1] = (bf16_t)(lo.y * QSCALE);
      v[2] = (bf16_t)(lo.z * QSCALE); v[3] = (bf16_t)(lo.w * QSCALE);
      v[4] = (bf16_t)(hi.x * QSCALE); v[5] = (bf16_t)(hi.y * QSCALE);
      v[6] = (bf16_t)(hi.z * QSCALE); v[7] = (bf16_t)(hi.w * QSCALE);
      aq[rb][t] = v;
    }
  }

  float lsumL[2][4] = {{0.f,0.f,0.f,0.f},{0.f,0.f,0.f,0.f}};
  f32x4 o[2][4] = {};
  const int cA = ((quad ^ (col & 7)) << 3);   // phys 16B slot for logical slot `quad`, row `col`

  // prologue: stage tile 0 (k0=0 for every block) into buf 0
#pragma unroll
  for (int c = 0; c < 4; ++c) {
    load16(ksrc0 + (size_t)(16 * c) * HD, Klds[0] + wave * 512 + c * 1024);
    load16(vsrc0 + (size_t)(16 * c) * Lc, Vlds[0] + wave * 512 + c * 1024);
  }

  for (int ti = 0; ti < ntot; ++ti) {
    const int buf = ti & 1;
    __syncthreads();                  // buf ready; prior reads of other buf done

    if (ti + 1 < ntot) {              // prefetch next tile (in flight across compute)
      const int kn = (ti + 1 < ntA) ? (ti + 1) * 64 : q0;
      bf16_t* kd = Klds[1 - buf] + wave * 512;
      bf16_t* vd = Vlds[1 - buf] + wave * 512;
#pragma unroll
      for (int c = 0; c < 4; ++c) {
        load16(ksrc0 + (size_t)(kn + 16 * c) * HD, kd + c * 1024);
        load16(vsrc0 + (size_t)(16 * c) * Lc + kn, vd + c * 1024);
      }
    }

    const bf16_t* kb = Klds[buf];
    const bf16_t* vb = Vlds[buf];
    const int k0 = (ti < ntA) ? ti * 64 : q0;

    // ---- S = Q K^T : K frags loaded once, used by both row-blocks ----
    f32x4 sf[2][4] = {};
#pragma unroll
    for (int kg = 0; kg < 4; ++kg) {
      const bf16_t* krow = kb + (kg * 16 + col) * 64;
      bf16x8 k0f = *(const bf16x8*)(krow + cA);
      bf16x8 k1f = *(const bf16x8*)(krow + (cA ^ 32));
#pragma unroll
      for (int rb = 0; rb < 2; ++rb) {
        sf[rb][kg] = MFMA16(aq[rb][0], k0f, sf[rb][kg]);
        sf[rb][kg] = MFMA16(aq[rb][1], k1f, sf[rb][kg]);
      }
    }

    // mode: 0 = unmasked (wave bound), 1 = per-row kend, 2 = diagonal chunk rule
    const int mode = (testblk && ti >= ntA) ? 2 : ((k0 + 64 <= kfull_end) ? 0 : 1);
    if (mode == 1) {
#pragma unroll
      for (int kg = 0; kg < 4; ++kg) {
        const int kgv = k0 + kg * 16 + col;
#pragma unroll
        for (int rb = 0; rb < 2; ++rb)
#pragma unroll
          for (int r = 0; r < 4; ++r)
            if (kgv >= kend[rb][r]) sf[rb][kg][r] = -1e30f;
      }
    } else if (mode == 2) {
#pragma unroll
      for (int kg = 0; kg < 4; ++kg) {
        const int kgv = k0 + kg * 16 + col;
#pragma unroll
        for (int rb = 0; rb < 2; ++rb)
#pragma unroll
          for (int r = 0; r < 4; ++r)
            if (kgv < cstart[rb][r] || kgv > qir[rb][r]) sf[rb][kg][r] = -1e30f;
      }
    }

    // ---- exp2 + P write (rows rb*16+quad*4+r, XOR 16B-slot swizzle) ----
    bf16_t* pw = Plds[wave];
#pragma unroll
    for (int rb = 0; rb < 2; ++rb) {
#pragma unroll
      for (int kg = 0; kg < 4; ++kg) {
#pragma unroll
        for (int r = 0; r < 4; ++r) {
          float p = __builtin_amdgcn_exp2f(sf[rb][kg][r]);
          lsumL[rb][r] += p;
          const int row = rb * 16 + quad * 4 + r;
          pw[row * 64 + (((kg * 2 + (col >> 3)) ^ (row & 7)) << 3) + (col & 7)] = (bf16_t)p;
        }
      }
    }
    // P A-frags: row-block rb reads P rows rb*16+col, slots quad / 4+quad
    bf16x8 pa[2][2];
#pragma unroll
    for (int rb = 0; rb < 2; ++rb) {
      pa[rb][0] = *(const bf16x8*)&pw[(rb * 16 + col) * 64 + cA];
      pa[rb][1] = *(const bf16x8*)&pw[(rb * 16 + col) * 64 + (cA ^ 32)];
    }

    // ---- O += P V : V frags loaded once, used by both row-blocks ----
#pragma unroll
    for (int t = 0; t < 4; ++t) {
      const bf16_t* vrow = vb + (t * 16 + col) * 64;
      bf16x8 v0 = *(const bf16x8*)(vrow + cA);
      bf16x8 v1 = *(const bf16x8*)(vrow + (cA ^ 32));
#pragma unroll
      for (int rb = 0; rb < 2; ++rb) {
        o[rb][t] = MFMA16(pa[rb][0], v0, o[rb][t]);
        o[rb][t] = MFMA16(pa[rb][1], v1, o[rb][t]);
      }
    }
  }

  // ---- epilogue: reduce lsum across the 16 cols, normalize, store ----
#pragma unroll
  for (int rb = 0; rb < 2; ++rb) {
#pragma unroll
    for (int r = 0; r < 4; ++r) {
      float rs = lsumL[rb][r];
      rs += __shfl_xor(rs, 1);
      rs += __shfl_xor(rs, 2);
      rs += __shfl_xor(rs, 4);
      rs += __shfl_xor(rs, 8);
      float inv = 1.f / rs;
      int qi = qw + rb * 16 + quad * 4 + r;
      float* op = OUT + ((size_t)b * Lc + qi) * HD + (size_t)h * Dc + col;
      op[0]  = o[rb][0][r] * inv;
      op[16] = o[rb][1][r] * inv;
      op[32] = o[rb][2][r] * inv;
      op[48] = o[rb][3][r] * inv;
    }
  }
}

extern "C" void kernel_launch(void* const* d_in, const int* in_sizes, int n_in,
                              void* d_out, int out_size, void* d_ws, size_t ws_size,
                              hipStream_t stream) {
  const float* Q   = (const float*)d_in[0];
  const float* K   = (const float*)d_in[1];
  const float* V   = (const float*)d_in[2];
  const int*   ATT = (const int*)d_in[3];
  float* OUT = (float*)d_out;
  (void)in_sizes; (void)n_in; (void)out_size; (void)ws_size;

  const size_t NE = (size_t)Bc * Lc * Hc * Dc;   // 4,194,304
  bf16_t* Kb = (bf16_t*)d_ws;                    // 8 MB
  bf16_t* Vt = Kb + NE;                          // 8 MB

  prep_kv<<<dim3(2048 + 1024), dim3(256), 0, stream>>>(K, V, Kb, Vt);
  continual_attn<<<dim3(Bc * Hc * 32), dim3(128), 0, stream>>>(Q, Kb, Vt, ATT, OUT);
}